// Round 2
// baseline (513.341 us; speedup 1.0000x reference)
//
#include <hip/hip_runtime.h>

// Shapes (fixed by the reference):
//   x:  (N=32, C=384, H=56, W=56)  -> (n, c, p) with HW=3136 = 49*64
//   gf: (N=32, M=8, D=768)
//   W_kv: (E=768, D=768), b_kv: (768,)
//   kv[n][m][e] = clip(sum_d gf[n][m][d]*W[e][d] + b[e], 0, 6)
//   K = kv[..., :384], V = kv[..., 384:]
//   scores[n,p,k] = sum_c x[n,c,p]*K[n,k,c]; attn = softmax_k
//   out[n,c,p] = x[n,c,p] + sum_k attn[n,p,k]*V[n,k,c]

#define NC 384
#define HWP 3136
#define DD 768
#define MM 8
#define EE 768

// ---------------- Kernel 1: KV projection + ReLU6 (unchanged) ----------------
__global__ __launch_bounds__(256) void kv_kernel(const float* __restrict__ gf,
                                                 const float* __restrict__ Wk,
                                                 const float* __restrict__ bk,
                                                 float* __restrict__ kv) {
    __shared__ float g[MM * DD];  // 24 KB
    const int n = blockIdx.y;
    const int et = blockIdx.x;   // 0..11
    const int t = threadIdx.x;

    const float* gfn = gf + (size_t)n * (MM * DD);
    for (int i = t; i < MM * DD; i += 256) g[i] = gfn[i];
    __syncthreads();

    const int e = et * 64 + (t & 63);
    const int mb = (t >> 6) * 2;  // wave-uniform m pair

    const float4* w4 = (const float4*)(Wk + (size_t)e * DD);
    const float4* g0 = (const float4*)(g + (mb + 0) * DD);
    const float4* g1 = (const float4*)(g + (mb + 1) * DD);

    float a0 = 0.f, a1 = 0.f;
    #pragma unroll 8
    for (int i = 0; i < DD / 4; ++i) {
        const float4 w = w4[i];
        const float4 v0 = g0[i];
        const float4 v1 = g1[i];
        a0 += w.x * v0.x + w.y * v0.y + w.z * v0.z + w.w * v0.w;
        a1 += w.x * v1.x + w.y * v1.y + w.z * v1.z + w.w * v1.w;
    }
    const float bv = bk[e];
    float* o = kv + (size_t)n * (MM * EE);
    o[(mb + 0) * EE + e] = fminf(fmaxf(a0 + bv, 0.f), 6.f);
    o[(mb + 1) * EE + e] = fminf(fmaxf(a1 + bv, 0.f), 6.f);
}

// ---------------- Kernel 2: fused attention + residual ----------------
// grid (49, 32), block 128 = 2 waves. Block = (n, 64 positions); each WAVE
// autonomously owns 32 positions x all 384 channels:
//   lane&7  -> position quad (float4 of 4 consecutive positions)
//   lane>>3 -> channel group g (8 groups x 48 channels)
// Every x/out access is float4: 64 lanes x 16B = 1KB/inst, 8 segments of
// 128B, every line fully consumed. Score reduction over g is IN-WAVE
// (shfl_xor 8/16/32); only ONE barrier (kv staging, L2-fast loads only).
// kvs layout: [half][k*416 + g*52 + j], j<48. Group stride 52 words: the 8
// b128 read addrs/wave hit banks {0,20,8,28,16,4,24,12}+0..3 = all 32 banks
// exactly once -> conflict-free 8-lane broadcast reads.
// LDS 26 KB -> 6 blocks/CU (12 waves). x is re-read in the epilogue (L2/L3
// resident; keeping 192 values live would need 192 VGPRs).
__global__ __launch_bounds__(128, 3) void attn_kernel(const float* __restrict__ x,
                                                      const float* __restrict__ kv,
                                                      float* __restrict__ out) {
    __shared__ float kvs[6656];  // 26 KB

    const int n = blockIdx.y;
    const int tile = blockIdx.x;     // 0..48
    const int t = threadIdx.x;       // 0..127
    const int lane = t & 63;
    const int w = t >> 6;            // wave 0..1
    const int g = lane >> 3;         // channel group 0..7
    const int c0 = g * 48;
    const int pos0 = tile * 64 + w * 32 + (lane & 7) * 4;

    // stage this n's K/V into padded layout (float4 global + float4 LDS writes)
    const float4* kvn4 = (const float4*)(kv + (size_t)n * (MM * EE));
    #pragma unroll
    for (int r = 0; r < 12; ++r) {
        const int f = t + r * 128;        // float4 index 0..1535
        const int k = f / 192;
        const int e4 = f - k * 192;       // 0..191
        const int half = (e4 >= 96) ? 1 : 0;
        const int c4 = e4 - half * 96;    // 0..95
        const int g2 = c4 / 12;
        const int j4 = c4 - g2 * 12;
        *(float4*)&kvs[half * 3328 + k * 416 + g2 * 52 + j4 * 4] = kvn4[f];
    }
    __syncthreads();

    // scores: stream my 48 channels x 4 positions (float4 loads, post-barrier)
    const float* xp = x + (size_t)n * NC * HWP + (size_t)c0 * HWP + pos0;
    float acc[8][4];
    #pragma unroll
    for (int k = 0; k < 8; ++k)
        #pragma unroll
        for (int p = 0; p < 4; ++p) acc[k][p] = 0.f;

    const float* kbase = &kvs[g * 52];
    #pragma unroll
    for (int i4 = 0; i4 < 12; ++i4) {
        const float4 xa = *(const float4*)(xp + (size_t)(i4 * 4 + 0) * HWP);
        const float4 xb = *(const float4*)(xp + (size_t)(i4 * 4 + 1) * HWP);
        const float4 xc = *(const float4*)(xp + (size_t)(i4 * 4 + 2) * HWP);
        const float4 xd = *(const float4*)(xp + (size_t)(i4 * 4 + 3) * HWP);
        #pragma unroll
        for (int k = 0; k < 8; ++k) {
            const float4 kk = *(const float4*)&kbase[k * 416 + i4 * 4];
            acc[k][0] += xa.x * kk.x + xb.x * kk.y + xc.x * kk.z + xd.x * kk.w;
            acc[k][1] += xa.y * kk.x + xb.y * kk.y + xc.y * kk.z + xd.y * kk.w;
            acc[k][2] += xa.z * kk.x + xb.z * kk.y + xc.z * kk.z + xd.z * kk.w;
            acc[k][3] += xa.w * kk.x + xb.w * kk.y + xc.w * kk.z + xd.w * kk.w;
        }
    }

    // in-wave reduce across the 8 channel groups (lane bits 3,4,5)
    #pragma unroll
    for (int k = 0; k < 8; ++k) {
        #pragma unroll
        for (int p = 0; p < 4; ++p) {
            acc[k][p] += __shfl_xor(acc[k][p], 8, 64);
            acc[k][p] += __shfl_xor(acc[k][p], 16, 64);
            acc[k][p] += __shfl_xor(acc[k][p], 32, 64);
        }
    }

    // softmax over k for each of my 4 positions (redundant x8 across g, fine)
    #pragma unroll
    for (int p = 0; p < 4; ++p) {
        float mx = acc[0][p];
        #pragma unroll
        for (int k = 1; k < 8; ++k) mx = fmaxf(mx, acc[k][p]);
        float su = 0.f;
        #pragma unroll
        for (int k = 0; k < 8; ++k) { acc[k][p] = __expf(acc[k][p] - mx); su += acc[k][p]; }
        const float inv = 1.f / su;
        #pragma unroll
        for (int k = 0; k < 8; ++k) acc[k][p] *= inv;
    }

    // epilogue: out = x + sum_k aw[k]*V[k][c]; x re-read (L2/L3-resident)
    float* op = out + (size_t)n * NC * HWP + (size_t)c0 * HWP + pos0;
    const float* vbase = &kvs[3328 + g * 52];
    #pragma unroll 6
    for (int i4 = 0; i4 < 12; ++i4) {
        float4 oa = *(const float4*)(xp + (size_t)(i4 * 4 + 0) * HWP);
        float4 ob = *(const float4*)(xp + (size_t)(i4 * 4 + 1) * HWP);
        float4 oc = *(const float4*)(xp + (size_t)(i4 * 4 + 2) * HWP);
        float4 od = *(const float4*)(xp + (size_t)(i4 * 4 + 3) * HWP);
        #pragma unroll
        for (int k = 0; k < 8; ++k) {
            const float4 vv = *(const float4*)&vbase[k * 416 + i4 * 4];
            oa.x += acc[k][0] * vv.x; oa.y += acc[k][1] * vv.x;
            oa.z += acc[k][2] * vv.x; oa.w += acc[k][3] * vv.x;
            ob.x += acc[k][0] * vv.y; ob.y += acc[k][1] * vv.y;
            ob.z += acc[k][2] * vv.y; ob.w += acc[k][3] * vv.y;
            oc.x += acc[k][0] * vv.z; oc.y += acc[k][1] * vv.z;
            oc.z += acc[k][2] * vv.z; oc.w += acc[k][3] * vv.z;
            od.x += acc[k][0] * vv.w; od.y += acc[k][1] * vv.w;
            od.z += acc[k][2] * vv.w; od.w += acc[k][3] * vv.w;
        }
        *(float4*)(op + (size_t)(i4 * 4 + 0) * HWP) = oa;
        *(float4*)(op + (size_t)(i4 * 4 + 1) * HWP) = ob;
        *(float4*)(op + (size_t)(i4 * 4 + 2) * HWP) = oc;
        *(float4*)(op + (size_t)(i4 * 4 + 3) * HWP) = od;
    }
}

extern "C" void kernel_launch(void* const* d_in, const int* in_sizes, int n_in,
                              void* d_out, int out_size, void* d_ws, size_t ws_size,
                              hipStream_t stream) {
    const float* x  = (const float*)d_in[0];
    const float* gf = (const float*)d_in[1];
    const float* Wk = (const float*)d_in[2];
    const float* bk = (const float*)d_in[3];
    float* out = (float*)d_out;
    float* kv = (float*)d_ws;  // 32*8*768 floats = 768 KB

    kv_kernel<<<dim3(12, 32), 256, 0, stream>>>(gf, Wk, bk, kv);
    attn_kernel<<<dim3(49, 32), 128, 0, stream>>>(x, kv, out);
}

// Round 3
// 317.791 us; speedup vs baseline: 1.6153x; 1.6153x over previous
//
#include <hip/hip_runtime.h>

// Shapes (fixed by the reference):
//   x:  (N=32, C=384, H=56, W=56)  -> (n, c, p) with HW=3136 = 98*32
//   gf: (N=32, M=8, D=768)
//   W_kv: (E=768, D=768), b_kv: (768,)
//   kv[n][m][e] = clip(sum_d gf[n][m][d]*W[e][d] + b[e], 0, 6)
//   K = kv[..., :384], V = kv[..., 384:]
//   scores[n,p,k] = sum_c x[n,c,p]*K[n,k,c]; attn = softmax_k
//   out[n,c,p] = x[n,c,p] + sum_k attn[n,p,k]*V[n,k,c]

#define NC 384
#define HWP 3136
#define DD 768
#define MM 8
#define EE 768

// ---------------- Kernel 1: KV projection + ReLU6 (unchanged) ----------------
__global__ __launch_bounds__(256) void kv_kernel(const float* __restrict__ gf,
                                                 const float* __restrict__ Wk,
                                                 const float* __restrict__ bk,
                                                 float* __restrict__ kv) {
    __shared__ float g[MM * DD];  // 24 KB
    const int n = blockIdx.y;
    const int et = blockIdx.x;   // 0..11
    const int t = threadIdx.x;

    const float* gfn = gf + (size_t)n * (MM * DD);
    for (int i = t; i < MM * DD; i += 256) g[i] = gfn[i];
    __syncthreads();

    const int e = et * 64 + (t & 63);
    const int mb = (t >> 6) * 2;  // wave-uniform m pair

    const float4* w4 = (const float4*)(Wk + (size_t)e * DD);
    const float4* g0 = (const float4*)(g + (mb + 0) * DD);
    const float4* g1 = (const float4*)(g + (mb + 1) * DD);

    float a0 = 0.f, a1 = 0.f;
    #pragma unroll 8
    for (int i = 0; i < DD / 4; ++i) {
        const float4 w = w4[i];
        const float4 v0 = g0[i];
        const float4 v1 = g1[i];
        a0 += w.x * v0.x + w.y * v0.y + w.z * v0.z + w.w * v0.w;
        a1 += w.x * v1.x + w.y * v1.y + w.z * v1.z + w.w * v1.w;
    }
    const float bv = bk[e];
    float* o = kv + (size_t)n * (MM * EE);
    o[(mb + 0) * EE + e] = fminf(fmaxf(a0 + bv, 0.f), 6.f);
    o[(mb + 1) * EE + e] = fminf(fmaxf(a1 + bv, 0.f), 6.f);
}

// ---------------- Kernel 2: fused attention + residual ----------------
// Round-0 mapping (proven best memory pattern), two fixes:
//  (1) x loads issued AFTER the staging barrier (sched_barrier fence keeps
//      them there): the barrier drain waits only on 6 L2-hit kv loads, not
//      24 HBM-latency x loads -> no block-wide phase-lock on HBM latency.
//  (2) dense kvs layout [half][k][c] (24 KB, no padding): per-wave K/V read
//      banks {0,8,16,24}+4*i4, disjoint spans -> conflict-free broadcast;
//      staging is a straight float4 copy (consecutive lanes, no conflicts).
// grid (98, 32), block 256 = 4 waves. Block = (n, 32 positions).
// Thread = (p2 = t&15: pair of consecutive positions -> float2, 128B wave
// segments; gq = t>>4: one of 16 24-channel groups).
// xr = 24 float2 = 48 VGPRs, live through the epilogue (no x re-read).
__global__ __launch_bounds__(256, 4) void attn_kernel(const float* __restrict__ x,
                                                      const float* __restrict__ kv,
                                                      float* __restrict__ out) {
    __shared__ float kvs[6144];     // 24 KB: [half*3072 + k*384 + c]
    __shared__ float sc[4][8][32];  // 4 KB: per-wave partial scores [w][k][pos]

    const int n = blockIdx.y;
    const int tile = blockIdx.x;     // 0..97
    const int t = threadIdx.x;
    const int p2 = t & 15;           // position pair
    const int gq = t >> 4;           // channel group (0..15)
    const int w = t >> 6;            // wave
    const int c0 = gq * 24;
    const int pos0 = tile * 32 + p2 * 2;

    // stage this n's K/V into dense [half][k][c] layout (pure float4 copy)
    const float4* kvn4 = (const float4*)(kv + (size_t)n * (MM * EE));
    float4* kvs4 = (float4*)kvs;
    #pragma unroll
    for (int r = 0; r < 6; ++r) {
        const int f = t + r * 256;        // float4 index 0..1535
        const int k = f / 192;
        const int e4 = f - k * 192;       // 0..191
        const int half = (e4 >= 96) ? 1 : 0;
        const int c4 = e4 - half * 96;    // 0..95
        kvs4[half * 768 + k * 96 + c4] = kvn4[f];
    }
    __syncthreads();
    __builtin_amdgcn_sched_barrier(0);  // keep x loads below the barrier

    // load my 24 channels x 2 positions of x (float2, 8B/lane, 128B segments)
    // issued post-barrier: each wave waits on its own loads, overlapped with
    // the first K ds_reads instead of serialized behind the barrier drain.
    const float* xp = x + (size_t)n * NC * HWP + (size_t)c0 * HWP + pos0;
    float2 xr[24];
    #pragma unroll
    for (int i = 0; i < 24; ++i) xr[i] = *(const float2*)(xp + (size_t)i * HWP);

    // partial scores over my 24 channels (K as broadcast float4 LDS reads)
    float accx[8], accy[8];
    #pragma unroll
    for (int k = 0; k < 8; ++k) { accx[k] = 0.f; accy[k] = 0.f; }

    const float* kbase = &kvs[gq * 24];
    #pragma unroll
    for (int i4 = 0; i4 < 6; ++i4) {
        const float2 x0 = xr[i4 * 4 + 0];
        const float2 x1 = xr[i4 * 4 + 1];
        const float2 x2 = xr[i4 * 4 + 2];
        const float2 x3 = xr[i4 * 4 + 3];
        #pragma unroll
        for (int k = 0; k < 8; ++k) {
            const float4 kk = *(const float4*)&kbase[k * 384 + i4 * 4];
            accx[k] += x0.x * kk.x + x1.x * kk.y + x2.x * kk.z + x3.x * kk.w;
            accy[k] += x0.y * kk.x + x1.y * kk.y + x2.y * kk.z + x3.y * kk.w;
        }
    }

    // in-wave reduce across the wave's 4 channel groups (lane bits 4,5)
    #pragma unroll
    for (int k = 0; k < 8; ++k) {
        accx[k] += __shfl_xor(accx[k], 16, 64);
        accx[k] += __shfl_xor(accx[k], 32, 64);
        accy[k] += __shfl_xor(accy[k], 16, 64);
        accy[k] += __shfl_xor(accy[k], 32, 64);
    }
    if ((t & 48) == 0) {  // lanes 0..15 of each wave hold the wave-partials
        #pragma unroll
        for (int k = 0; k < 8; ++k)
            *(float2*)&sc[w][k][p2 * 2] = make_float2(accx[k], accy[k]);
    }
    __syncthreads();

    // every thread: sum the 4 wave-partials for its 2 positions, softmax over k
    float sx[8], sy[8];
    #pragma unroll
    for (int k = 0; k < 8; ++k) {
        float2 s = *(const float2*)&sc[0][k][p2 * 2];
        #pragma unroll
        for (int ww = 1; ww < 4; ++ww) {
            const float2 q = *(const float2*)&sc[ww][k][p2 * 2];
            s.x += q.x; s.y += q.y;
        }
        sx[k] = s.x; sy[k] = s.y;
    }
    {
        float mx = sx[0], my = sy[0];
        #pragma unroll
        for (int k = 1; k < 8; ++k) { mx = fmaxf(mx, sx[k]); my = fmaxf(my, sy[k]); }
        float sux = 0.f, suy = 0.f;
        #pragma unroll
        for (int k = 0; k < 8; ++k) {
            sx[k] = __expf(sx[k] - mx); sux += sx[k];
            sy[k] = __expf(sy[k] - my); suy += sy[k];
        }
        const float ix = 1.f / sux, iy = 1.f / suy;
        #pragma unroll
        for (int k = 0; k < 8; ++k) { sx[k] *= ix; sy[k] *= iy; }
    }

    // epilogue: out = x + sum_k aw[k]*V[k][c]; xr is live, no x re-read
    float* op = out + (size_t)n * NC * HWP + (size_t)c0 * HWP + pos0;
    const float* vbase = &kvs[3072 + gq * 24];
    #pragma unroll
    for (int i4 = 0; i4 < 6; ++i4) {
        float2 o0 = xr[i4 * 4 + 0];
        float2 o1 = xr[i4 * 4 + 1];
        float2 o2 = xr[i4 * 4 + 2];
        float2 o3 = xr[i4 * 4 + 3];
        #pragma unroll
        for (int k = 0; k < 8; ++k) {
            const float4 vv = *(const float4*)&vbase[k * 384 + i4 * 4];
            o0.x += sx[k] * vv.x; o0.y += sy[k] * vv.x;
            o1.x += sx[k] * vv.y; o1.y += sy[k] * vv.y;
            o2.x += sx[k] * vv.z; o2.y += sy[k] * vv.z;
            o3.x += sx[k] * vv.w; o3.y += sy[k] * vv.w;
        }
        *(float2*)(op + (size_t)(i4 * 4 + 0) * HWP) = o0;
        *(float2*)(op + (size_t)(i4 * 4 + 1) * HWP) = o1;
        *(float2*)(op + (size_t)(i4 * 4 + 2) * HWP) = o2;
        *(float2*)(op + (size_t)(i4 * 4 + 3) * HWP) = o3;
    }
}

extern "C" void kernel_launch(void* const* d_in, const int* in_sizes, int n_in,
                              void* d_out, int out_size, void* d_ws, size_t ws_size,
                              hipStream_t stream) {
    const float* x  = (const float*)d_in[0];
    const float* gf = (const float*)d_in[1];
    const float* Wk = (const float*)d_in[2];
    const float* bk = (const float*)d_in[3];
    float* out = (float*)d_out;
    float* kv = (float*)d_ws;  // 32*8*768 floats = 768 KB

    kv_kernel<<<dim3(12, 32), 256, 0, stream>>>(gf, Wk, bk, kv);
    attn_kernel<<<dim3(98, 32), 256, 0, stream>>>(x, kv, out);
}

// Round 5
// 287.869 us; speedup vs baseline: 1.7832x; 1.1039x over previous
//
#include <hip/hip_runtime.h>

// Shapes (fixed by the reference):
//   x:  (N=32, C=384, H=56, W=56)  -> (n, c, p) with HW=3136 = 98*32
//   gf: (N=32, M=8, D=768)
//   W_kv: (E=768, D=768)  <-- E = 2*C = 768 TOTAL rows. b_kv: (768,)
//   kv[n][m][e] = clip(sum_d gf[n][m][d]*W[e][d] + b[e], 0, 6)
//   K = kv[..., :384], V = kv[..., 384:]
//   scores[n,p,k] = sum_c x[n,c,p]*K[n,k,c]; attn = softmax_k
//   out[n,c,p] = x[n,c,p] + sum_k attn[n,p,k]*V[n,k,c]

#define NC 384
#define HWP 3136
#define DD 768
#define MM 8
#define EE 768

// ---------------- Kernel 1: KV projection + ReLU6 (rewritten, bounds fixed) ----
// Old version: lane-per-row W loads = 64x 16B scattered segments/inst, 384
// blocks (1.5/CU) -> ~215 us (dominated the total!).
// New: grid (48, 16), block 256 = 4 waves; block = (16 e-rows, 2 n's).
//   48 blocks x 16 rows = 768 = EE exactly.
// Wave w owns rows e = bx*16 + w*4 + grp (grp = lane>>4), lq = lane&15.
// Lane holds W[e][j*64 + lq*4 .. +3], j=0..11 (48 VGPRs, loaded ONCE per
// block; per instruction = 4 groups x 256B contiguous segments, coalesced).
// Per n: stage gf[n] in LDS (straight float4 copy), dot 8 m's from LDS
// (16 distinct float4 per read = 2-way bank alias = free), 4-level
// shfl_xor reduce within the 16-lane group, lanes lq<8 store kv[n][lq][e].
// 768 blocks = 3/CU evenly; W total 2.3 MB -> L2/L3-resident re-reads.
__global__ __launch_bounds__(256) void kv_kernel(const float* __restrict__ gf,
                                                 const float* __restrict__ Wk,
                                                 const float* __restrict__ bk,
                                                 float* __restrict__ kv) {
    __shared__ float g[MM * DD];  // 24 KB
    const int t = threadIdx.x;
    const int lane = t & 63;
    const int w = t >> 6;
    const int grp = lane >> 4;       // row within the wave's quad (0..3)
    const int lq = lane & 15;        // d-slice owner within the group
    const int e = blockIdx.x * 16 + w * 4 + grp;   // 0..767

    // W row slices: live in VGPRs across the n-loop (read once per block)
    float4 wr[12];
    const float* wrow = Wk + (size_t)e * DD;
    #pragma unroll
    for (int j = 0; j < 12; ++j)
        wr[j] = *(const float4*)(wrow + j * 64 + lq * 4);
    const float bv = bk[e];

    #pragma unroll
    for (int ni = 0; ni < 2; ++ni) {
        const int n = blockIdx.y * 2 + ni;           // 0..31
        if (ni) __syncthreads();  // protect previous iteration's LDS reads
        const float4* gfn = (const float4*)(gf + (size_t)n * (MM * DD));
        float4* g4 = (float4*)g;
        #pragma unroll
        for (int r = 0; r < 6; ++r) g4[t + r * 256] = gfn[t + r * 256];
        __syncthreads();

        float res = 0.f;
        #pragma unroll
        for (int m = 0; m < 8; ++m) {
            float acc = 0.f;
            #pragma unroll
            for (int j = 0; j < 12; ++j) {
                const float4 gg = *(const float4*)&g[m * DD + j * 64 + lq * 4];
                acc += wr[j].x * gg.x + wr[j].y * gg.y
                     + wr[j].z * gg.z + wr[j].w * gg.w;
            }
            // reduce the 16 d-slice partials within the group (lane bits 0..3)
            acc += __shfl_xor(acc, 1, 64);
            acc += __shfl_xor(acc, 2, 64);
            acc += __shfl_xor(acc, 4, 64);
            acc += __shfl_xor(acc, 8, 64);
            if (lq == m) res = acc;
        }
        if (lq < 8)
            kv[(size_t)n * (MM * EE) + (size_t)lq * EE + e] =
                fminf(fmaxf(res + bv, 0.f), 6.f);
    }
}

// ---------------- Kernel 2: fused attention + residual (UNCHANGED r3) ----------------
__global__ __launch_bounds__(256, 4) void attn_kernel(const float* __restrict__ x,
                                                      const float* __restrict__ kv,
                                                      float* __restrict__ out) {
    __shared__ float kvs[6144];     // 24 KB: [half*3072 + k*384 + c]
    __shared__ float sc[4][8][32];  // 4 KB: per-wave partial scores [w][k][pos]

    const int n = blockIdx.y;
    const int tile = blockIdx.x;     // 0..97
    const int t = threadIdx.x;
    const int p2 = t & 15;           // position pair
    const int gq = t >> 4;           // channel group (0..15)
    const int w = t >> 6;            // wave
    const int c0 = gq * 24;
    const int pos0 = tile * 32 + p2 * 2;

    // stage this n's K/V into dense [half][k][c] layout (pure float4 copy)
    const float4* kvn4 = (const float4*)(kv + (size_t)n * (MM * EE));
    float4* kvs4 = (float4*)kvs;
    #pragma unroll
    for (int r = 0; r < 6; ++r) {
        const int f = t + r * 256;        // float4 index 0..1535
        const int k = f / 192;
        const int e4 = f - k * 192;       // 0..191
        const int half = (e4 >= 96) ? 1 : 0;
        const int c4 = e4 - half * 96;    // 0..95
        kvs4[half * 768 + k * 96 + c4] = kvn4[f];
    }
    __syncthreads();
    __builtin_amdgcn_sched_barrier(0);  // keep x loads below the barrier

    // load my 24 channels x 2 positions of x (float2, 8B/lane, 128B segments)
    const float* xp = x + (size_t)n * NC * HWP + (size_t)c0 * HWP + pos0;
    float2 xr[24];
    #pragma unroll
    for (int i = 0; i < 24; ++i) xr[i] = *(const float2*)(xp + (size_t)i * HWP);

    // partial scores over my 24 channels (K as broadcast float4 LDS reads)
    float accx[8], accy[8];
    #pragma unroll
    for (int k = 0; k < 8; ++k) { accx[k] = 0.f; accy[k] = 0.f; }

    const float* kbase = &kvs[gq * 24];
    #pragma unroll
    for (int i4 = 0; i4 < 6; ++i4) {
        const float2 x0 = xr[i4 * 4 + 0];
        const float2 x1 = xr[i4 * 4 + 1];
        const float2 x2 = xr[i4 * 4 + 2];
        const float2 x3 = xr[i4 * 4 + 3];
        #pragma unroll
        for (int k = 0; k < 8; ++k) {
            const float4 kk = *(const float4*)&kbase[k * 384 + i4 * 4];
            accx[k] += x0.x * kk.x + x1.x * kk.y + x2.x * kk.z + x3.x * kk.w;
            accy[k] += x0.y * kk.x + x1.y * kk.y + x2.y * kk.z + x3.y * kk.w;
        }
    }

    // in-wave reduce across the wave's 4 channel groups (lane bits 4,5)
    #pragma unroll
    for (int k = 0; k < 8; ++k) {
        accx[k] += __shfl_xor(accx[k], 16, 64);
        accx[k] += __shfl_xor(accx[k], 32, 64);
        accy[k] += __shfl_xor(accy[k], 16, 64);
        accy[k] += __shfl_xor(accy[k], 32, 64);
    }
    if ((t & 48) == 0) {  // lanes 0..15 of each wave hold the wave-partials
        #pragma unroll
        for (int k = 0; k < 8; ++k)
            *(float2*)&sc[w][k][p2 * 2] = make_float2(accx[k], accy[k]);
    }
    __syncthreads();

    // every thread: sum the 4 wave-partials for its 2 positions, softmax over k
    float sx[8], sy[8];
    #pragma unroll
    for (int k = 0; k < 8; ++k) {
        float2 s = *(const float2*)&sc[0][k][p2 * 2];
        #pragma unroll
        for (int ww = 1; ww < 4; ++ww) {
            const float2 q = *(const float2*)&sc[ww][k][p2 * 2];
            s.x += q.x; s.y += q.y;
        }
        sx[k] = s.x; sy[k] = s.y;
    }
    {
        float mx = sx[0], my = sy[0];
        #pragma unroll
        for (int k = 1; k < 8; ++k) { mx = fmaxf(mx, sx[k]); my = fmaxf(my, sy[k]); }
        float sux = 0.f, suy = 0.f;
        #pragma unroll
        for (int k = 0; k < 8; ++k) {
            sx[k] = __expf(sx[k] - mx); sux += sx[k];
            sy[k] = __expf(sy[k] - my); suy += sy[k];
        }
        const float ix = 1.f / sux, iy = 1.f / suy;
        #pragma unroll
        for (int k = 0; k < 8; ++k) { sx[k] *= ix; sy[k] *= iy; }
    }

    // epilogue: out = x + sum_k aw[k]*V[k][c]; xr is live, no x re-read
    float* op = out + (size_t)n * NC * HWP + (size_t)c0 * HWP + pos0;
    const float* vbase = &kvs[3072 + gq * 24];
    #pragma unroll
    for (int i4 = 0; i4 < 6; ++i4) {
        float2 o0 = xr[i4 * 4 + 0];
        float2 o1 = xr[i4 * 4 + 1];
        float2 o2 = xr[i4 * 4 + 2];
        float2 o3 = xr[i4 * 4 + 3];
        #pragma unroll
        for (int k = 0; k < 8; ++k) {
            const float4 vv = *(const float4*)&vbase[k * 384 + i4 * 4];
            o0.x += sx[k] * vv.x; o0.y += sy[k] * vv.x;
            o1.x += sx[k] * vv.y; o1.y += sy[k] * vv.y;
            o2.x += sx[k] * vv.z; o2.y += sy[k] * vv.z;
            o3.x += sx[k] * vv.w; o3.y += sy[k] * vv.w;
        }
        *(float2*)(op + (size_t)(i4 * 4 + 0) * HWP) = o0;
        *(float2*)(op + (size_t)(i4 * 4 + 1) * HWP) = o1;
        *(float2*)(op + (size_t)(i4 * 4 + 2) * HWP) = o2;
        *(float2*)(op + (size_t)(i4 * 4 + 3) * HWP) = o3;
    }
}

extern "C" void kernel_launch(void* const* d_in, const int* in_sizes, int n_in,
                              void* d_out, int out_size, void* d_ws, size_t ws_size,
                              hipStream_t stream) {
    const float* x  = (const float*)d_in[0];
    const float* gf = (const float*)d_in[1];
    const float* Wk = (const float*)d_in[2];
    const float* bk = (const float*)d_in[3];
    float* out = (float*)d_out;
    float* kv = (float*)d_ws;  // 32*8*768 floats = 768 KB

    kv_kernel<<<dim3(48, 16), 256, 0, stream>>>(gf, Wk, bk, kv);
    attn_kernel<<<dim3(98, 32), 256, 0, stream>>>(x, kv, out);
}